// Round 8
// baseline (294.431 us; speedup 1.0000x reference)
//
#include <hip/hip_runtime.h>
#include <hip/hip_bf16.h>

#define HD 128
#define G 32           // edge chunks (= CSR replicas)
#define RLOG 5
#define PR 8           // bin-range windows (grid = G x PR = 256 blocks)
#define LEAKY 0.2f
#define LN_EPS 1e-5f
#define TILE 4096      // scan tile: 256 threads x 16 items

// ---- bf16 helpers (manual, RNE) ----
__device__ __forceinline__ unsigned short bfr(float f) {
    unsigned int b = __float_as_uint(f);
    return (unsigned short)((b + 0x7fffu + ((b >> 16) & 1u)) >> 16);
}
__device__ __forceinline__ float blo(unsigned int u) { return __uint_as_float(u << 16); }
__device__ __forceinline__ float bhi(unsigned int u) { return __uint_as_float(u & 0xffff0000u); }

// ---------- fp32 -> bf16 conversion (ego) ----------
__global__ __launch_bounds__(256) void f32_to_bf16(
    const float* __restrict__ x, unsigned short* __restrict__ y, int n4) {
    int i = blockIdx.x * 256 + threadIdx.x;
    if (i >= n4) return;
    float4 f = ((const float4*)x)[i];
    ushort4 u;
    u.x = bfr(f.x); u.y = bfr(f.y); u.z = bfr(f.z); u.w = bfr(f.w);
    ((ushort4*)y)[i] = u;
}

// ---------- CSR build: LDS histogram (zero global atomics) ----------
// 1D grid of G*PR blocks; p = blk & (PR-1), g = blk >> 3. Packed 2x16-bit
// LDS counters; dumps counts to cnt[g*n + b].
__global__ __launch_bounds__(1024) void histo_lds(
    const int* __restrict__ rows, const int* __restrict__ cols,
    int* __restrict__ cnt_r, int* __restrict__ cnt_c, int nnz, int n) {
    __shared__ unsigned ldsR[3136], ldsC[3136];
    int p = blockIdx.x & (PR - 1);
    int g = blockIdx.x >> 3;                // PR == 8
    int per = (n + PR - 1) / PR;            // 6250
    int lo = p * per;
    int hi = min(lo + per, n);
    int nb = hi - lo;
    int nw = (nb + 1) >> 1;
    for (int j = threadIdx.x; j < nw; j += 1024) { ldsR[j] = 0u; ldsC[j] = 0u; }
    __syncthreads();

    int chunk = (nnz + G - 1) / G;          // 25000
    int beg = g * chunk;
    int end = min(beg + chunk, nnz);
    for (int i = beg + threadIdx.x; i < end; i += 1024) {
        unsigned obr = (unsigned)(rows[i] - lo);
        unsigned obc = (unsigned)(cols[i] - lo);
        if (obr < (unsigned)nb) atomicAdd(&ldsR[obr >> 1], 1u << ((obr & 1) * 16));
        if (obc < (unsigned)nb) atomicAdd(&ldsC[obc >> 1], 1u << ((obc & 1) * 16));
    }
    __syncthreads();
    for (int j = threadIdx.x; j < nb; j += 1024) {
        int sh = (j & 1) * 16;
        cnt_r[(size_t)g * n + lo + j] = (ldsR[j >> 1] >> sh) & 0xffffu;
        cnt_c[(size_t)g * n + lo + j] = (ldsC[j >> 1] >> sh) & 0xffffu;
    }
}

// Exclusive scan over logical order p = bin*G + chunk, reading cnt[g*n+b].
__global__ __launch_bounds__(256) void scan_sum(
    const int* __restrict__ cnt, int* __restrict__ partials, int n, int tiles) {
    int a = blockIdx.y;
    const int* base = cnt + (size_t)a * n * G;
    int M = n * G;
    int t0 = blockIdx.x * TILE + threadIdx.x * 16;
    int s = 0;
    #pragma unroll
    for (int j = 0; j < 16; ++j) {
        int p = t0 + j;
        if (p < M) s += base[(p & (G - 1)) * n + (p >> RLOG)];
    }
    #pragma unroll
    for (int off = 32; off; off >>= 1) s += __shfl_xor(s, off);
    __shared__ int ws[4];
    int lane = threadIdx.x & 63, wid = threadIdx.x >> 6;
    if (lane == 0) ws[wid] = s;
    __syncthreads();
    if (threadIdx.x == 0)
        partials[a * tiles + blockIdx.x] = ws[0] + ws[1] + ws[2] + ws[3];
}

// Wave-parallel exclusive scan of tile partials (tiles <= 512), 2 waves.
__global__ __launch_bounds__(128) void scan_partials(
    int* __restrict__ partials, int tiles,
    int* __restrict__ rp_r, int* __restrict__ rp_c, int n, int nnz) {
    int wid = threadIdx.x >> 6, lane = threadIdx.x & 63;
    int* p = partials + wid * tiles;
    int v[8], s = 0;
    #pragma unroll
    for (int j = 0; j < 8; ++j) {
        int idx = lane * 8 + j;
        v[j] = (idx < tiles) ? p[idx] : 0;
        s += v[j];
    }
    int incl = s;
    #pragma unroll
    for (int off = 1; off < 64; off <<= 1) {
        int t = __shfl_up(incl, off);
        if (lane >= off) incl += t;
    }
    int excl = incl - s;
    #pragma unroll
    for (int j = 0; j < 8; ++j) {
        int idx = lane * 8 + j;
        if (idx < tiles) p[idx] = excl;
        excl += v[j];
    }
    if (lane == 0) (wid ? rp_c : rp_r)[n] = nnz;
}

// Re-scan tiles, convert cnt -> exclusive base offsets in-place,
// emit rp[b] (chunk-0 offset = bin start).
__global__ __launch_bounds__(256) void scan_apply(
    int* __restrict__ cnt, const int* __restrict__ partials,
    int* __restrict__ rp_r, int* __restrict__ rp_c, int n, int tiles) {
    int a = blockIdx.y;
    int* base = cnt + (size_t)a * n * G;
    int* rp = a ? rp_c : rp_r;
    int M = n * G;
    int t0 = blockIdx.x * TILE + threadIdx.x * 16;
    int v[16];
    int s = 0;
    #pragma unroll
    for (int j = 0; j < 16; ++j) {
        int p = t0 + j;
        v[j] = (p < M) ? base[(p & (G - 1)) * n + (p >> RLOG)] : 0;
        s += v[j];
    }
    int lane = threadIdx.x & 63, wid = threadIdx.x >> 6;
    int incl = s;
    #pragma unroll
    for (int off = 1; off < 64; off <<= 1) {
        int t = __shfl_up(incl, off);
        if (lane >= off) incl += t;
    }
    __shared__ int wsum[4], woff[4];
    if (lane == 63) wsum[wid] = incl;
    __syncthreads();
    if (threadIdx.x == 0) {
        int run = 0;
        #pragma unroll
        for (int w = 0; w < 4; ++w) { woff[w] = run; run += wsum[w]; }
    }
    __syncthreads();
    int excl = partials[a * tiles + blockIdx.x] + woff[wid] + incl - s;
    #pragma unroll
    for (int j = 0; j < 16; ++j) {
        int p = t0 + j;
        if (p < M) {
            int b = p >> RLOG, r = p & (G - 1);
            base[r * n + b] = excl;
            if (r == 0) rp[b] = excl;
            excl += v[j];
        }
    }
}

// Fill via rank recomputation. 1D grid, p = blk & 7 -> all 32 chunk-blocks of
// window p share an XCD (round-robin dispatch heuristic), so the scattered
// 4 B ent stores assemble full lines inside one L2. Entry = (bf16(val)<<16)|other.
__global__ __launch_bounds__(1024) void fill_lds(
    const int* __restrict__ rows, const int* __restrict__ cols,
    const float* __restrict__ vals,
    const int* __restrict__ base_r, const int* __restrict__ base_c,
    unsigned* __restrict__ ent_r, unsigned* __restrict__ ent_c, int nnz, int n) {
    __shared__ unsigned ldsR[3136], ldsC[3136];
    int p = blockIdx.x & (PR - 1);
    int g = blockIdx.x >> 3;
    int per = (n + PR - 1) / PR;
    int lo = p * per;
    int hi = min(lo + per, n);
    int nb = hi - lo;
    int nw = (nb + 1) >> 1;
    for (int j = threadIdx.x; j < nw; j += 1024) { ldsR[j] = 0u; ldsC[j] = 0u; }
    __syncthreads();

    int chunk = (nnz + G - 1) / G;
    int beg = g * chunk;
    int end = min(beg + chunk, nnz);
    for (int i = beg + threadIdx.x; i < end; i += 1024) {
        int ro = rows[i], co = cols[i];
        unsigned obr = (unsigned)(ro - lo);
        unsigned obc = (unsigned)(co - lo);
        if ((obr < (unsigned)nb) | (obc < (unsigned)nb)) {
            unsigned vb = (unsigned)bfr(vals[i]) << 16;
            if (obr < (unsigned)nb) {
                int sh = (obr & 1) * 16;
                unsigned old = atomicAdd(&ldsR[obr >> 1], 1u << sh);
                int rank = (old >> sh) & 0xffffu;
                ent_r[base_r[(size_t)g * n + ro] + rank] = vb | (unsigned)co;
            }
            if (obc < (unsigned)nb) {
                int sh = (obc & 1) * 16;
                unsigned old = atomicAdd(&ldsC[obc >> 1], 1u << sh);
                int rank = (old >> sh) & 0xffffu;
                ent_c[base_c[(size_t)g * n + co] + rank] = vb | (unsigned)ro;
            }
        }
    }
}

// ---------- bf16-gather SpMM (+ optional fused leaky/LN/residual) ----------
// One wave per output row. Quarter-wave (16 lanes) x 16 B (8 bf16) covers a
// 256 B row; the 4 quarters process interleaved edges (4-wide unrolled).
// Entry decode: val = bhi(e), src = e & 0xffff.
// post: 0 = none (bf16 out), 1 = leaky+LN+res (bf16 out), 2 = LN+res (fp32 out).
__global__ __launch_bounds__(256) void spmm_bf(
    const unsigned short* __restrict__ x, const int* __restrict__ rp,
    const unsigned* __restrict__ ent,
    const float* __restrict__ res, const float* __restrict__ gamma,
    const float* __restrict__ beta,
    unsigned short* __restrict__ out_bf, float* __restrict__ out_f32,
    int n, int post) {
    int wid = threadIdx.x >> 6, lane = threadIdx.x & 63;
    int row = blockIdx.x * 4 + wid;
    if (row >= n) return;
    int quarter = lane >> 4, q = lane & 15;
    int beg = rp[row], end = rp[row + 1];
    float acc[8];
    #pragma unroll
    for (int k = 0; k < 8; ++k) acc[k] = 0.f;

    int i = beg + quarter;
    for (; i + 12 < end; i += 16) {
        unsigned e0 = ent[i], e1 = ent[i + 4], e2 = ent[i + 8], e3 = ent[i + 12];
        uint4 u0 = ((const uint4*)(x + (size_t)(e0 & 0xffffu) * HD))[q];
        uint4 u1 = ((const uint4*)(x + (size_t)(e1 & 0xffffu) * HD))[q];
        uint4 u2 = ((const uint4*)(x + (size_t)(e2 & 0xffffu) * HD))[q];
        uint4 u3 = ((const uint4*)(x + (size_t)(e3 & 0xffffu) * HD))[q];
        float v0 = bhi(e0), v1 = bhi(e1), v2 = bhi(e2), v3 = bhi(e3);
        acc[0] += v0 * blo(u0.x) + v1 * blo(u1.x);
        acc[1] += v0 * bhi(u0.x) + v1 * bhi(u1.x);
        acc[2] += v0 * blo(u0.y) + v1 * blo(u1.y);
        acc[3] += v0 * bhi(u0.y) + v1 * bhi(u1.y);
        acc[4] += v0 * blo(u0.z) + v1 * blo(u1.z);
        acc[5] += v0 * bhi(u0.z) + v1 * bhi(u1.z);
        acc[6] += v0 * blo(u0.w) + v1 * blo(u1.w);
        acc[7] += v0 * bhi(u0.w) + v1 * bhi(u1.w);
        acc[0] += v2 * blo(u2.x) + v3 * blo(u3.x);
        acc[1] += v2 * bhi(u2.x) + v3 * bhi(u3.x);
        acc[2] += v2 * blo(u2.y) + v3 * blo(u3.y);
        acc[3] += v2 * bhi(u2.y) + v3 * bhi(u3.y);
        acc[4] += v2 * blo(u2.z) + v3 * blo(u3.z);
        acc[5] += v2 * bhi(u2.z) + v3 * bhi(u3.z);
        acc[6] += v2 * blo(u2.w) + v3 * blo(u3.w);
        acc[7] += v2 * bhi(u2.w) + v3 * bhi(u3.w);
    }
    for (; i < end; i += 4) {
        unsigned e0 = ent[i];
        uint4 u0 = ((const uint4*)(x + (size_t)(e0 & 0xffffu) * HD))[q];
        float v0 = bhi(e0);
        acc[0] += v0 * blo(u0.x);
        acc[1] += v0 * bhi(u0.x);
        acc[2] += v0 * blo(u0.y);
        acc[3] += v0 * bhi(u0.y);
        acc[4] += v0 * blo(u0.z);
        acc[5] += v0 * bhi(u0.z);
        acc[6] += v0 * blo(u0.w);
        acc[7] += v0 * bhi(u0.w);
    }
    // combine the 4 quarters
    #pragma unroll
    for (int k = 0; k < 8; ++k) {
        acc[k] += __shfl_xor(acc[k], 16);
        acc[k] += __shfl_xor(acc[k], 32);
    }
    if (quarter != 0) return;

    if (post == 0) {
        uint4 s;
        s.x = (unsigned)bfr(acc[0]) | ((unsigned)bfr(acc[1]) << 16);
        s.y = (unsigned)bfr(acc[2]) | ((unsigned)bfr(acc[3]) << 16);
        s.z = (unsigned)bfr(acc[4]) | ((unsigned)bfr(acc[5]) << 16);
        s.w = (unsigned)bfr(acc[6]) | ((unsigned)bfr(acc[7]) << 16);
        ((uint4*)(out_bf + (size_t)row * HD))[q] = s;
        return;
    }
    if (post == 1) {
        #pragma unroll
        for (int k = 0; k < 8; ++k) acc[k] = acc[k] >= 0.f ? acc[k] : LEAKY * acc[k];
    }
    float t = 0.f;
    #pragma unroll
    for (int k = 0; k < 8; ++k) t += acc[k];
    #pragma unroll
    for (int off = 1; off < 16; off <<= 1) t += __shfl_xor(t, off);
    float mu = t * (1.f / HD);
    float d[8], vs = 0.f;
    #pragma unroll
    for (int k = 0; k < 8; ++k) { d[k] = acc[k] - mu; vs += d[k] * d[k]; }
    #pragma unroll
    for (int off = 1; off < 16; off <<= 1) vs += __shfl_xor(vs, off);
    float inv = rsqrtf(vs * (1.f / HD) + LN_EPS);

    float4 g0 = ((const float4*)gamma)[2 * q], g1 = ((const float4*)gamma)[2 * q + 1];
    float4 b0 = ((const float4*)beta)[2 * q],  b1 = ((const float4*)beta)[2 * q + 1];
    float4 r0 = ((const float4*)(res + (size_t)row * HD))[2 * q];
    float4 r1 = ((const float4*)(res + (size_t)row * HD))[2 * q + 1];
    float o[8];
    o[0] = d[0] * inv * g0.x + b0.x + r0.x;
    o[1] = d[1] * inv * g0.y + b0.y + r0.y;
    o[2] = d[2] * inv * g0.z + b0.z + r0.z;
    o[3] = d[3] * inv * g0.w + b0.w + r0.w;
    o[4] = d[4] * inv * g1.x + b1.x + r1.x;
    o[5] = d[5] * inv * g1.y + b1.y + r1.y;
    o[6] = d[6] * inv * g1.z + b1.z + r1.z;
    o[7] = d[7] * inv * g1.w + b1.w + r1.w;
    if (post == 1) {
        uint4 s;
        s.x = (unsigned)bfr(o[0]) | ((unsigned)bfr(o[1]) << 16);
        s.y = (unsigned)bfr(o[2]) | ((unsigned)bfr(o[3]) << 16);
        s.z = (unsigned)bfr(o[4]) | ((unsigned)bfr(o[5]) << 16);
        s.w = (unsigned)bfr(o[6]) | ((unsigned)bfr(o[7]) << 16);
        ((uint4*)(out_bf + (size_t)row * HD))[q] = s;
    } else {
        float4 s0 = {o[0], o[1], o[2], o[3]};
        float4 s1 = {o[4], o[5], o[6], o[7]};
        ((float4*)(out_f32 + (size_t)row * HD))[2 * q] = s0;
        ((float4*)(out_f32 + (size_t)row * HD))[2 * q + 1] = s1;
    }
}

extern "C" void kernel_launch(void* const* d_in, const int* in_sizes, int n_in,
                              void* d_out, int out_size, void* d_ws, size_t ws_size,
                              hipStream_t stream) {
    const float* ego   = (const float*)d_in[0];
    const float* vals  = (const float*)d_in[1];
    const float* gamma = (const float*)d_in[2];
    const float* beta  = (const float*)d_in[3];
    const int*   rows  = (const int*)d_in[4];
    const int*   cols  = (const int*)d_in[5];

    const int N   = in_sizes[0] / HD;   // 50000 (must be < 65536 for 4B entries)
    const int NNZ = in_sizes[1];        // 800000

    float* out = (float*)d_out;
    char* w = (char*)d_ws;
    unsigned short* ego_bf = (unsigned short*)w; w += (size_t)N * HD * 2;
    unsigned short* bufA   = (unsigned short*)w; w += (size_t)N * HD * 2;
    unsigned short* bufB   = (unsigned short*)w; w += (size_t)N * HD * 2;  // aliases cnt
    int*  rp_r = (int*)w;  w += (size_t)(N + 4) * 4;
    int*  rp_c = (int*)w;  w += (size_t)(N + 4) * 4;
    unsigned* ent_r = (unsigned*)w; w += (size_t)NNZ * 4;
    unsigned* ent_c = (unsigned*)w; w += (size_t)NNZ * 4;
    int*  partials = (int*)w; w += 8192;

    // cnt arrays alias bufB (2*G*N*4 = 12.8 MB = bufB size; last read by
    // fill_lds, which runs before spmm #2 writes bufB).
    int* cnt_r  = (int*)bufB;
    int* cnt_c  = cnt_r + (size_t)G * N;

    const int tiles = (N * G + TILE - 1) / TILE;   // 391 (<=512 for scan_partials)

    // ---- build both CSRs + bf16 ego ----
    f32_to_bf16<<<(N * HD / 4 + 255) / 256, 256, 0, stream>>>(ego, ego_bf, N * HD / 4);
    histo_lds<<<G * PR, 1024, 0, stream>>>(rows, cols, cnt_r, cnt_c, NNZ, N);
    scan_sum<<<dim3(tiles, 2), 256, 0, stream>>>(cnt_r, partials, N, tiles);
    scan_partials<<<1, 128, 0, stream>>>(partials, tiles, rp_r, rp_c, N, NNZ);
    scan_apply<<<dim3(tiles, 2), 256, 0, stream>>>(cnt_r, partials, rp_r, rp_c, N, tiles);
    fill_lds<<<G * PR, 1024, 0, stream>>>(rows, cols, vals, cnt_r, cnt_c,
                                          ent_r, ent_c, NNZ, N);

    const int sblocks = (N + 3) / 4;

    // ---- layer 0 ----
    spmm_bf<<<sblocks, 256, 0, stream>>>(ego_bf, rp_c, ent_c,
                                         nullptr, nullptr, nullptr, bufA, nullptr, N, 0);
    spmm_bf<<<sblocks, 256, 0, stream>>>(bufA, rp_r, ent_r,
                                         ego, gamma, beta, bufB, nullptr, N, 1);
    // ---- layer 1 ----
    spmm_bf<<<sblocks, 256, 0, stream>>>(bufB, rp_c, ent_c,
                                         nullptr, nullptr, nullptr, bufA, nullptr, N, 0);
    spmm_bf<<<sblocks, 256, 0, stream>>>(bufA, rp_r, ent_r,
                                         ego, gamma + HD, beta + HD, nullptr, out, N, 2);
}

// Round 9
// 266.423 us; speedup vs baseline: 1.1051x; 1.1051x over previous
//
#include <hip/hip_runtime.h>
#include <hip/hip_bf16.h>

#define HD 128
#define PB 256         // partition blocks
#define LEAKY 0.2f
#define LN_EPS 1e-5f

// ---- bf16 helpers (manual, RNE) ----
__device__ __forceinline__ unsigned short bfr(float f) {
    unsigned int b = __float_as_uint(f);
    return (unsigned short)((b + 0x7fffu + ((b >> 16) & 1u)) >> 16);
}
__device__ __forceinline__ float blo(unsigned int u) { return __uint_as_float(u << 16); }
__device__ __forceinline__ float bhi(unsigned int u) { return __uint_as_float(u & 0xffff0000u); }

// ---------- fp32 -> bf16 conversion (ego) ----------
__global__ __launch_bounds__(256) void f32_to_bf16(
    const float* __restrict__ x, unsigned short* __restrict__ y, int n4) {
    int i = blockIdx.x * 256 + threadIdx.x;
    if (i >= n4) return;
    float4 f = ((const float4*)x)[i];
    ushort4 u;
    u.x = bfr(f.x); u.y = bfr(f.y); u.z = bfr(f.z); u.w = bfr(f.w);
    ((ushort4*)y)[i] = u;
}

// ---------- CSR build: two-level bucket partition (zero global atomics) ----
// Bucket of node b = b >> 10. counts layout: counts[dir*PB*64 + blk*64 + bkt].

// k1: per-block bucket counts for both directions.
__global__ __launch_bounds__(256) void part_count(
    const int* __restrict__ rows, const int* __restrict__ cols,
    int* __restrict__ counts, int nnz) {
    __shared__ int cR[64], cC[64];
    if (threadIdx.x < 64) { cR[threadIdx.x] = 0; cC[threadIdx.x] = 0; }
    __syncthreads();
    int chunk = (nnz + PB - 1) / PB;
    int beg = blockIdx.x * chunk;
    int end = min(beg + chunk, nnz);
    for (int i = beg + threadIdx.x; i < end; i += 256) {
        atomicAdd(&cR[rows[i] >> 10], 1);
        atomicAdd(&cC[cols[i] >> 10], 1);
    }
    __syncthreads();
    if (threadIdx.x < 64) {
        counts[(size_t)blockIdx.x * 64 + threadIdx.x] = cR[threadIdx.x];
        counts[(size_t)PB * 64 + blockIdx.x * 64 + threadIdx.x] = cC[threadIdx.x];
    }
}

// k2a: for each (dir,bucket), exclusive scan over PB block counts (in-place
// counts -> offsets), emit totals[dir*64+bkt]. One wave per block.
__global__ __launch_bounds__(64) void part_off(
    int* __restrict__ counts, int* __restrict__ totals) {
    int bkt = blockIdx.x, dir = blockIdx.y, lane = threadIdx.x;
    int* p = counts + (size_t)dir * PB * 64;
    int v[4], s = 0;
    #pragma unroll
    for (int j = 0; j < 4; ++j) {
        int blk = lane * 4 + j;
        v[j] = p[(size_t)blk * 64 + bkt];
        s += v[j];
    }
    int incl = s;
    #pragma unroll
    for (int off = 1; off < 64; off <<= 1) {
        int t = __shfl_up(incl, off);
        if (lane >= off) incl += t;
    }
    int excl = incl - s;
    #pragma unroll
    for (int j = 0; j < 4; ++j) {
        int blk = lane * 4 + j;
        p[(size_t)blk * 64 + bkt] = excl;
        excl += v[j];
    }
    if (lane == 63) totals[dir * 64 + bkt] = incl;
}

// k2b: bucket bases (exclusive scan of totals per dir; one wave per dir),
// plus rp[N] = nnz.
__global__ __launch_bounds__(128) void base_scan(
    const int* __restrict__ totals, int* __restrict__ bases,
    int* __restrict__ rp_r, int* __restrict__ rp_c, int nbk, int n, int nnz) {
    int dir = threadIdx.x >> 6, lane = threadIdx.x & 63;
    int v = (lane < nbk) ? totals[dir * 64 + lane] : 0;
    int incl = v;
    #pragma unroll
    for (int off = 1; off < 64; off <<= 1) {
        int t = __shfl_up(incl, off);
        if (lane >= off) incl += t;
    }
    bases[dir * 64 + lane] = incl - v;
    if (lane == 0) (dir ? rp_c : rp_r)[n] = nnz;
}

// k3: scatter edges into bucket-major staging: stg[dir] entry = (payload, bin),
// payload = other | (bf16(val) << 16). Per-(block,bucket) destination ranges
// are contiguous -> block-exclusive line assembly.
__global__ __launch_bounds__(256) void part_scatter(
    const int* __restrict__ rows, const int* __restrict__ cols,
    const float* __restrict__ vals,
    const int* __restrict__ counts, const int* __restrict__ bases,
    uint2* __restrict__ stg_r, uint2* __restrict__ stg_c, int nnz) {
    __shared__ int cR[64], cC[64], wbR[64], wbC[64];
    if (threadIdx.x < 64) {
        cR[threadIdx.x] = 0; cC[threadIdx.x] = 0;
        wbR[threadIdx.x] = bases[threadIdx.x] +
            counts[(size_t)blockIdx.x * 64 + threadIdx.x];
        wbC[threadIdx.x] = bases[64 + threadIdx.x] +
            counts[(size_t)PB * 64 + blockIdx.x * 64 + threadIdx.x];
    }
    __syncthreads();
    int chunk = (nnz + PB - 1) / PB;
    int beg = blockIdx.x * chunk;
    int end = min(beg + chunk, nnz);
    for (int i = beg + threadIdx.x; i < end; i += 256) {
        int ro = rows[i], co = cols[i];
        unsigned vb = (unsigned)bfr(vals[i]) << 16;
        int rk = atomicAdd(&cR[ro >> 10], 1);
        stg_r[wbR[ro >> 10] + rk] = make_uint2(vb | (unsigned)co, (unsigned)ro);
        int ck = atomicAdd(&cC[co >> 10], 1);
        stg_c[wbC[co >> 10] + ck] = make_uint2(vb | (unsigned)ro, (unsigned)co);
    }
}

// k4: one block per (dir,bucket). Count bins in LDS, scan, write rp
// coalesced, scatter final 4 B entries within the block's own ent window
// (single-CU -> single-L2 -> full-line writebacks).
__global__ __launch_bounds__(1024) void bucket_build(
    const uint2* __restrict__ stg_r, const uint2* __restrict__ stg_c,
    const int* __restrict__ totals, const int* __restrict__ bases,
    unsigned* __restrict__ ent_r, unsigned* __restrict__ ent_c,
    int* __restrict__ rp_r, int* __restrict__ rp_c, int n) {
    __shared__ int cnt[1024];
    __shared__ int wsum[16], woff[16];
    int bkt = blockIdx.x, dir = blockIdx.y;
    const uint2* stg = dir ? stg_c : stg_r;
    unsigned* ent = dir ? ent_c : ent_r;
    int* rp = dir ? rp_c : rp_r;
    int base = bases[dir * 64 + bkt];
    int total = totals[dir * 64 + bkt];
    int lo = bkt << 10;
    int nb = min(1024, n - lo);
    cnt[threadIdx.x] = 0;
    __syncthreads();
    for (int i = threadIdx.x; i < total; i += 1024)
        atomicAdd(&cnt[(int)stg[base + i].y - lo], 1);
    __syncthreads();
    // exclusive scan of cnt[0..1024)
    int lane = threadIdx.x & 63, wid = threadIdx.x >> 6;
    int v = cnt[threadIdx.x];
    int incl = v;
    #pragma unroll
    for (int off = 1; off < 64; off <<= 1) {
        int t = __shfl_up(incl, off);
        if (lane >= off) incl += t;
    }
    if (lane == 63) wsum[wid] = incl;
    __syncthreads();
    if (threadIdx.x == 0) {
        int run = 0;
        #pragma unroll
        for (int w = 0; w < 16; ++w) { woff[w] = run; run += wsum[w]; }
    }
    __syncthreads();
    int excl = woff[wid] + incl - v;
    if (threadIdx.x < nb) rp[lo + threadIdx.x] = base + excl;
    cnt[threadIdx.x] = excl;           // own slot; becomes cursor
    __syncthreads();
    for (int i = threadIdx.x; i < total; i += 1024) {
        uint2 e = stg[base + i];
        int pos = atomicAdd(&cnt[(int)e.y - lo], 1);
        ent[base + pos] = e.x;
    }
}

// ---------- bf16-gather SpMM (+ optional fused leaky/LN/residual) ----------
// One wave per output row. Quarter-wave (16 lanes) x 16 B (8 bf16) covers a
// 256 B row; the 4 quarters process interleaved edges (4-wide unrolled).
// Entry decode: val = bhi(e), src = e & 0xffff.
// post: 0 = none (bf16 out), 1 = leaky+LN+res (bf16 out), 2 = LN+res (fp32 out).
__global__ __launch_bounds__(256) void spmm_bf(
    const unsigned short* __restrict__ x, const int* __restrict__ rp,
    const unsigned* __restrict__ ent,
    const float* __restrict__ res, const float* __restrict__ gamma,
    const float* __restrict__ beta,
    unsigned short* __restrict__ out_bf, float* __restrict__ out_f32,
    int n, int post) {
    int wid = threadIdx.x >> 6, lane = threadIdx.x & 63;
    int row = blockIdx.x * 4 + wid;
    if (row >= n) return;
    int quarter = lane >> 4, q = lane & 15;
    int beg = rp[row], end = rp[row + 1];
    float acc[8];
    #pragma unroll
    for (int k = 0; k < 8; ++k) acc[k] = 0.f;

    int i = beg + quarter;
    for (; i + 12 < end; i += 16) {
        unsigned e0 = ent[i], e1 = ent[i + 4], e2 = ent[i + 8], e3 = ent[i + 12];
        uint4 u0 = ((const uint4*)(x + (size_t)(e0 & 0xffffu) * HD))[q];
        uint4 u1 = ((const uint4*)(x + (size_t)(e1 & 0xffffu) * HD))[q];
        uint4 u2 = ((const uint4*)(x + (size_t)(e2 & 0xffffu) * HD))[q];
        uint4 u3 = ((const uint4*)(x + (size_t)(e3 & 0xffffu) * HD))[q];
        float v0 = bhi(e0), v1 = bhi(e1), v2 = bhi(e2), v3 = bhi(e3);
        acc[0] += v0 * blo(u0.x) + v1 * blo(u1.x);
        acc[1] += v0 * bhi(u0.x) + v1 * bhi(u1.x);
        acc[2] += v0 * blo(u0.y) + v1 * blo(u1.y);
        acc[3] += v0 * bhi(u0.y) + v1 * bhi(u1.y);
        acc[4] += v0 * blo(u0.z) + v1 * blo(u1.z);
        acc[5] += v0 * bhi(u0.z) + v1 * bhi(u1.z);
        acc[6] += v0 * blo(u0.w) + v1 * blo(u1.w);
        acc[7] += v0 * bhi(u0.w) + v1 * bhi(u1.w);
        acc[0] += v2 * blo(u2.x) + v3 * blo(u3.x);
        acc[1] += v2 * bhi(u2.x) + v3 * bhi(u3.x);
        acc[2] += v2 * blo(u2.y) + v3 * blo(u3.y);
        acc[3] += v2 * bhi(u2.y) + v3 * bhi(u3.y);
        acc[4] += v2 * blo(u2.z) + v3 * blo(u3.z);
        acc[5] += v2 * bhi(u2.z) + v3 * bhi(u3.z);
        acc[6] += v2 * blo(u2.w) + v3 * blo(u3.w);
        acc[7] += v2 * bhi(u2.w) + v3 * bhi(u3.w);
    }
    for (; i < end; i += 4) {
        unsigned e0 = ent[i];
        uint4 u0 = ((const uint4*)(x + (size_t)(e0 & 0xffffu) * HD))[q];
        float v0 = bhi(e0);
        acc[0] += v0 * blo(u0.x);
        acc[1] += v0 * bhi(u0.x);
        acc[2] += v0 * blo(u0.y);
        acc[3] += v0 * bhi(u0.y);
        acc[4] += v0 * blo(u0.z);
        acc[5] += v0 * bhi(u0.z);
        acc[6] += v0 * blo(u0.w);
        acc[7] += v0 * bhi(u0.w);
    }
    // combine the 4 quarters
    #pragma unroll
    for (int k = 0; k < 8; ++k) {
        acc[k] += __shfl_xor(acc[k], 16);
        acc[k] += __shfl_xor(acc[k], 32);
    }
    if (quarter != 0) return;

    if (post == 0) {
        uint4 s;
        s.x = (unsigned)bfr(acc[0]) | ((unsigned)bfr(acc[1]) << 16);
        s.y = (unsigned)bfr(acc[2]) | ((unsigned)bfr(acc[3]) << 16);
        s.z = (unsigned)bfr(acc[4]) | ((unsigned)bfr(acc[5]) << 16);
        s.w = (unsigned)bfr(acc[6]) | ((unsigned)bfr(acc[7]) << 16);
        ((uint4*)(out_bf + (size_t)row * HD))[q] = s;
        return;
    }
    if (post == 1) {
        #pragma unroll
        for (int k = 0; k < 8; ++k) acc[k] = acc[k] >= 0.f ? acc[k] : LEAKY * acc[k];
    }
    float t = 0.f;
    #pragma unroll
    for (int k = 0; k < 8; ++k) t += acc[k];
    #pragma unroll
    for (int off = 1; off < 16; off <<= 1) t += __shfl_xor(t, off);
    float mu = t * (1.f / HD);
    float d[8], vs = 0.f;
    #pragma unroll
    for (int k = 0; k < 8; ++k) { d[k] = acc[k] - mu; vs += d[k] * d[k]; }
    #pragma unroll
    for (int off = 1; off < 16; off <<= 1) vs += __shfl_xor(vs, off);
    float inv = rsqrtf(vs * (1.f / HD) + LN_EPS);

    float4 g0 = ((const float4*)gamma)[2 * q], g1 = ((const float4*)gamma)[2 * q + 1];
    float4 b0 = ((const float4*)beta)[2 * q],  b1 = ((const float4*)beta)[2 * q + 1];
    float4 r0 = ((const float4*)(res + (size_t)row * HD))[2 * q];
    float4 r1 = ((const float4*)(res + (size_t)row * HD))[2 * q + 1];
    float o[8];
    o[0] = d[0] * inv * g0.x + b0.x + r0.x;
    o[1] = d[1] * inv * g0.y + b0.y + r0.y;
    o[2] = d[2] * inv * g0.z + b0.z + r0.z;
    o[3] = d[3] * inv * g0.w + b0.w + r0.w;
    o[4] = d[4] * inv * g1.x + b1.x + r1.x;
    o[5] = d[5] * inv * g1.y + b1.y + r1.y;
    o[6] = d[6] * inv * g1.z + b1.z + r1.z;
    o[7] = d[7] * inv * g1.w + b1.w + r1.w;
    if (post == 1) {
        uint4 s;
        s.x = (unsigned)bfr(o[0]) | ((unsigned)bfr(o[1]) << 16);
        s.y = (unsigned)bfr(o[2]) | ((unsigned)bfr(o[3]) << 16);
        s.z = (unsigned)bfr(o[4]) | ((unsigned)bfr(o[5]) << 16);
        s.w = (unsigned)bfr(o[6]) | ((unsigned)bfr(o[7]) << 16);
        ((uint4*)(out_bf + (size_t)row * HD))[q] = s;
    } else {
        float4 s0 = {o[0], o[1], o[2], o[3]};
        float4 s1 = {o[4], o[5], o[6], o[7]};
        ((float4*)(out_f32 + (size_t)row * HD))[2 * q] = s0;
        ((float4*)(out_f32 + (size_t)row * HD))[2 * q + 1] = s1;
    }
}

extern "C" void kernel_launch(void* const* d_in, const int* in_sizes, int n_in,
                              void* d_out, int out_size, void* d_ws, size_t ws_size,
                              hipStream_t stream) {
    const float* ego   = (const float*)d_in[0];
    const float* vals  = (const float*)d_in[1];
    const float* gamma = (const float*)d_in[2];
    const float* beta  = (const float*)d_in[3];
    const int*   rows  = (const int*)d_in[4];
    const int*   cols  = (const int*)d_in[5];

    const int N   = in_sizes[0] / HD;   // 50000 (< 65536 for 16-bit node ids)
    const int NNZ = in_sizes[1];        // 800000
    const int NBK = (N + 1023) >> 10;   // 49 buckets (<= 64)

    float* out = (float*)d_out;
    char* w = (char*)d_ws;
    unsigned short* ego_bf = (unsigned short*)w; w += (size_t)N * HD * 2;
    unsigned short* bufA   = (unsigned short*)w; w += (size_t)N * HD * 2;
    unsigned short* bufB   = (unsigned short*)w; w += (size_t)N * HD * 2;  // aliases stg
    int*  rp_r = (int*)w;  w += (size_t)(N + 4) * 4;
    int*  rp_c = (int*)w;  w += (size_t)(N + 4) * 4;
    unsigned* ent_r = (unsigned*)w; w += (size_t)NNZ * 4;
    unsigned* ent_c = (unsigned*)w; w += (size_t)NNZ * 4;
    int* counts = (int*)w; w += (size_t)2 * PB * 64 * 4;
    int* totals = (int*)w; w += 128 * 4;
    int* bases  = (int*)w; w += 128 * 4;

    // staging aliases bufB (2*NNZ*8 = 12.8 MB = bufB size; consumed by
    // bucket_build, which runs before spmm #2 writes bufB).
    uint2* stg_r = (uint2*)bufB;
    uint2* stg_c = stg_r + NNZ;

    // ---- build both CSRs + bf16 ego ----
    f32_to_bf16<<<(N * HD / 4 + 255) / 256, 256, 0, stream>>>(ego, ego_bf, N * HD / 4);
    part_count<<<PB, 256, 0, stream>>>(rows, cols, counts, NNZ);
    part_off<<<dim3(NBK, 2), 64, 0, stream>>>(counts, totals);
    base_scan<<<1, 128, 0, stream>>>(totals, bases, rp_r, rp_c, NBK, N, NNZ);
    part_scatter<<<PB, 256, 0, stream>>>(rows, cols, vals, counts, bases,
                                         stg_r, stg_c, NNZ);
    bucket_build<<<dim3(NBK, 2), 1024, 0, stream>>>(stg_r, stg_c, totals, bases,
                                                    ent_r, ent_c, rp_r, rp_c, N);

    const int sblocks = (N + 3) / 4;

    // ---- layer 0 ----
    spmm_bf<<<sblocks, 256, 0, stream>>>(ego_bf, rp_c, ent_c,
                                         nullptr, nullptr, nullptr, bufA, nullptr, N, 0);
    spmm_bf<<<sblocks, 256, 0, stream>>>(bufA, rp_r, ent_r,
                                         ego, gamma, beta, bufB, nullptr, N, 1);
    // ---- layer 1 ----
    spmm_bf<<<sblocks, 256, 0, stream>>>(bufB, rp_c, ent_c,
                                         nullptr, nullptr, nullptr, bufA, nullptr, N, 0);
    spmm_bf<<<sblocks, 256, 0, stream>>>(bufA, rp_r, ent_r,
                                         ego, gamma + HD, beta + HD, nullptr, out, N, 2);
}